// Round 7
// baseline (889.168 us; speedup 1.0000x reference)
//
#include <hip/hip_runtime.h>
#include <hip/hip_bf16.h>

#define NROW 16384
#define NFEATC 512
#define NH1 256
#define NH2 128
#define NCLS 8

typedef __attribute__((ext_vector_type(8))) short short8;
typedef __attribute__((ext_vector_type(4))) float f32x4;

#define WAITV(n) asm volatile("s_waitcnt vmcnt(" #n ")" ::: "memory")
#define LGKM0    asm volatile("s_waitcnt lgkmcnt(0)" ::: "memory")
#define FENCE    asm volatile("" ::: "memory")

__device__ __forceinline__ ushort f2bf(float f) {
  union { float f; unsigned u; } v; v.f = f;
  unsigned r = v.u + 0x7FFFu + ((v.u >> 16) & 1u);
  return (ushort)(r >> 16);
}
__device__ __forceinline__ float bf2f(ushort h) {
  union { unsigned u; float f; } v; v.u = ((unsigned)h) << 16; return v.f;
}

// async 16-byte global -> LDS (dest = wave-uniform base + lane*16)
__device__ __forceinline__ void gl_lds16(const ushort* g, ushort* l) {
  __builtin_amdgcn_global_load_lds(
      (const __attribute__((address_space(1))) unsigned int*)g,
      (__attribute__((address_space(3))) unsigned int*)l, 16, 0, 0);
}

// in [K][N] fp32 -> out [N][K] bf16
__global__ __launch_bounds__(256) void transpose_conv(
    const float* __restrict__ in, ushort* __restrict__ out, int K, int N) {
  int idx = blockIdx.x * 256 + threadIdx.x;
  if (idx < K * N) {
    int k = idx / N, n = idx % N;
    out[(size_t)n * K + k] = f2bf(in[idx]);
  }
}

// ---------------------------------------------------------------------------
// gemm_pipe: reg-staged path for the small-K GEMMs (x@W1, h1@W2). Proven.
template<int BM, int BN, int WM, int WN, int KSPLIT, bool AFP32, int OUTM, int MINW>
__global__ __launch_bounds__(256, MINW) void gemm_pipe(
    const void* __restrict__ Ap, const ushort* __restrict__ BT,
    void* __restrict__ Outp, const float* __restrict__ bias,
    const int nm, const int nn, const int M, const int N, const int K)
{
  constexpr int BK = 64, LDSK = BK + 8;
  constexpr int MR = WM / 16, NR = WN / 16;
  constexpr int nWc = BN / WN;
  static_assert((BM / WM) * (BN / WN) == 4, "4 waves");
  constexpr int AELEM = BM * BK / 256, ATPR = BK / AELEM;
  constexpr int BELEM = BN * BK / 256, BTPR = BK / BELEM;
  constexpr int A4s = AFP32 ? AELEM / 4 : 1;
  constexpr int A8s = AFP32 ? 1 : AELEM / 8;
  constexpr int B8s = (BELEM >= 8) ? BELEM / 8 : 1;

  __shared__ ushort As[2][BM * LDSK];
  __shared__ ushort Bs[2][BN * LDSK];

  const int t = threadIdx.x, l = t & 63, wid = t >> 6;
  const int wr0 = (wid / nWc) * WM, wc0 = (wid % nWc) * WN;

  const int cpx = gridDim.x >> 3;
  const int flat = (blockIdx.x & 7) * cpx + (blockIdx.x >> 3);
  const int n_blk = flat % nn;
  const int m_blk = (flat / nn) % nm;
  const int ksl = flat / (nn * nm);
  const int bm0 = m_blk * BM, bn0 = n_blk * BN;
  const int kper = K / KSPLIT, kbase = ksl * kper;
  const int NT = kper / BK;

  const int ar = t / ATPR, ak = (t % ATPR) * AELEM;
  const int br = t / BTPR, bk = (t % BTPR) * BELEM;

  const float*  Af = (const float*)Ap + (size_t)(bm0 + ar) * K + kbase + ak;
  const ushort* Ab = (const ushort*)Ap + (size_t)(bm0 + ar) * K + kbase + ak;
  const ushort* Bp = BT + (size_t)(bn0 + br) * K + kbase + bk;

  f32x4 acc[MR][NR] = {};

  float4 aF[A4s];
  short8 aB[A8s];
  short8 bV[B8s];
  ushort4 b4;

  auto loadRegs = [&](int it) {
    const int ko = it * BK;
    if constexpr (AFP32) {
      #pragma unroll
      for (int c = 0; c < A4s; c++) aF[c] = *(const float4*)(Af + ko + 4 * c);
    } else {
      #pragma unroll
      for (int c = 0; c < A8s; c++) aB[c] = *(const short8*)(Ab + ko + 8 * c);
    }
    if constexpr (BELEM >= 8) {
      #pragma unroll
      for (int c = 0; c < B8s; c++) bV[c] = *(const short8*)(Bp + ko + 8 * c);
    } else {
      b4 = *(const ushort4*)(Bp + ko);
    }
  };

  auto writeLds = [&](int buf) {
    if constexpr (AFP32) {
      #pragma unroll
      for (int c = 0; c < A4s; c++) {
        ushort4 v;
        v.x = f2bf(aF[c].x); v.y = f2bf(aF[c].y);
        v.z = f2bf(aF[c].z); v.w = f2bf(aF[c].w);
        *(ushort4*)&As[buf][ar * LDSK + ak + 4 * c] = v;
      }
    } else {
      #pragma unroll
      for (int c = 0; c < A8s; c++)
        *(short8*)&As[buf][ar * LDSK + ak + 8 * c] = aB[c];
    }
    if constexpr (BELEM >= 8) {
      #pragma unroll
      for (int c = 0; c < B8s; c++)
        *(short8*)&Bs[buf][br * LDSK + bk + 8 * c] = bV[c];
    } else {
      *(ushort4*)&Bs[buf][br * LDSK + bk] = b4;
    }
  };

  auto compute = [&](int buf) {
    const int rr = l & 15;
    #pragma unroll
    for (int kk = 0; kk < 2; kk++) {
      const int kb = kk * 32 + (l >> 4) * 8;
      short8 af[MR], bfv[NR];
      #pragma unroll
      for (int m = 0; m < MR; m++)
        af[m] = *(short8*)&As[buf][(wr0 + m * 16 + rr) * LDSK + kb];
      #pragma unroll
      for (int n = 0; n < NR; n++)
        bfv[n] = *(short8*)&Bs[buf][(wc0 + n * 16 + rr) * LDSK + kb];
      #pragma unroll
      for (int m = 0; m < MR; m++)
        #pragma unroll
        for (int n = 0; n < NR; n++)
          acc[m][n] = __builtin_amdgcn_mfma_f32_16x16x32_bf16(af[m], bfv[n], acc[m][n], 0, 0, 0);
    }
  };

  loadRegs(0);
  writeLds(0);
  __syncthreads();
  for (int it = 0; it < NT; it++) {
    const int cur = it & 1;
    if (it + 1 < NT) loadRegs(it + 1);
    compute(cur);
    if (it + 1 < NT) writeLds(cur ^ 1);
    __syncthreads();
  }

  #pragma unroll
  for (int m = 0; m < MR; m++) {
    const int row = bm0 + wr0 + m * 16 + (l >> 4) * 4;
    #pragma unroll
    for (int n = 0; n < NR; n++) {
      const int col = bn0 + wc0 + n * 16 + (l & 15);
      if constexpr (OUTM == 1) {
        ushort4 v;
        v.x = f2bf(acc[m][n][0]); v.y = f2bf(acc[m][n][1]);
        v.z = f2bf(acc[m][n][2]); v.w = f2bf(acc[m][n][3]);
        *(ushort4*)((ushort*)Outp + (size_t)col * M + row) = v;
      } else {
        const float bv = bias[col];
        ushort* o = (ushort*)Outp;
        #pragma unroll
        for (int r = 0; r < 4; r++)
          o[(size_t)(row + r) * N + col] = f2bf(fmaxf(acc[m][n][r] + bv, 0.0f));
      }
    }
  }
}

// ---------------------------------------------------------------------------
// gemm_h1: part[4][16384][256] = adj(fp32) @ s1 ; also writes adjBF (bf16).
// 8 waves (512 thr), block 128 rows x 256 cols, BK=32, NT=128 per ksl (4).
// A: global fp32 -> regs (4 named sets, flight 3 iters) -> cvt -> ds_write
//    one iter ahead into 2 LDS bufs (+ adjBF store).
// B: global_load_lds into 4 LDS bufs (flight 2 iters, s1T slice is L2-hot).
// One raw s_barrier per iter; steady vmcnt(6); vmcnt(0) only for last 3 iters.
// LDS layout: tiles of [16 rows][32 k] stored as lane-linear 16B slots so
// ds_write/ds_read are lane*16B -> 2-way bank aliasing only (free).
#define H1_NT 128

__global__ __launch_bounds__(512, 2) void gemm_h1(
    const float* __restrict__ adj, const ushort* __restrict__ s1T,
    float* __restrict__ part, ushort* __restrict__ adjBF)
{
  __shared__ ushort As[2][4096];   // 2 bufs x 8 tiles x 512
  __shared__ ushort Bs[4][8192];   // 4 bufs x 16 tiles x 512

  const int t = threadIdx.x, l = t & 63, wid = t >> 6;
  const int rr = l & 15, hi = l >> 4;
  const int wr = wid >> 2, wc = wid & 3;       // wave grid 2M x 4N

  const int cpx = gridDim.x >> 3;
  const int flat = (blockIdx.x & 7) * cpx + (blockIdx.x >> 3);
  const int m_blk = flat & 127;
  const int ksl = flat >> 7;                   // 0..3
  const int bm0 = m_blk * 128;
  const int kbase = ksl * 4096;

  // A: thread t covers row (wid*16+rr), k-chunk hi*8 (8 fp32 = 32B)
  const float* Ap = adj + (size_t)(bm0 + wid * 16 + rr) * NROW + kbase + hi * 8;
  ushort* adjWp = adjBF + (size_t)(bm0 + wid * 16 + rr) * NROW + kbase + hi * 8;
  // B: wave w stages col-tiles 2w, 2w+1
  const ushort* Bp0 = s1T + (size_t)(wid * 32 + rr) * NROW + kbase + hi * 8;
  const ushort* Bp1 = s1T + (size_t)(wid * 32 + 16 + rr) * NROW + kbase + hi * 8;

  f32x4 acc[4][4] = {};
  float4 S0[2], S1[2], S2[2], S3[2];   // 4 named A reg-sets (rule #20)

  auto cvtwrite = [&](const float4* S, int k) {
    short8 v;
    v[0] = (short)f2bf(S[0].x); v[1] = (short)f2bf(S[0].y);
    v[2] = (short)f2bf(S[0].z); v[3] = (short)f2bf(S[0].w);
    v[4] = (short)f2bf(S[1].x); v[5] = (short)f2bf(S[1].y);
    v[6] = (short)f2bf(S[1].z); v[7] = (short)f2bf(S[1].w);
    *(short8*)&As[k & 1][t * 8] = v;          // lane-linear
    *(short8*)(adjWp + k * 32) = v;           // adjBF writeout
  };

  auto compute = [&](int ab, int bb) {
    short8 af[4], bf4[4];
    #pragma unroll
    for (int m = 0; m < 4; m++)
      af[m] = *(const short8*)&As[ab][(wr * 4 + m) * 512 + l * 8];
    #pragma unroll
    for (int n = 0; n < 4; n++)
      bf4[n] = *(const short8*)&Bs[bb][(wc * 4 + n) * 512 + l * 8];
    #pragma unroll
    for (int m = 0; m < 4; m++)
      #pragma unroll
      for (int n = 0; n < 4; n++)
        acc[m][n] = __builtin_amdgcn_mfma_f32_16x16x32_bf16(af[m], bf4[n], acc[m][n], 0, 0, 0);
  };

  // prologue: A(0..3) -> S0..S3 ; B(0),B(1) staged
  S0[0] = *(const float4*)(Ap + 0);   S0[1] = *(const float4*)(Ap + 4);
  S1[0] = *(const float4*)(Ap + 32);  S1[1] = *(const float4*)(Ap + 36);
  S2[0] = *(const float4*)(Ap + 64);  S2[1] = *(const float4*)(Ap + 68);
  S3[0] = *(const float4*)(Ap + 96);  S3[1] = *(const float4*)(Ap + 100);
  gl_lds16(Bp0 + 0,  &Bs[0][wid * 1024]);
  gl_lds16(Bp1 + 0,  &Bs[0][wid * 1024 + 512]);
  gl_lds16(Bp0 + 32, &Bs[1][wid * 1024]);
  gl_lds16(Bp1 + 32, &Bs[1][wid * 1024 + 512]);
  WAITV(10);                  // A(0) landed
  cvtwrite(S0, 0);

#define H1_ITER(T, SLD, SCV) {                                                 \
    const int t_ = (T);                                                        \
    if (t_ == 0) { WAITV(3); } else if (t_ < H1_NT - 3) { WAITV(6); }          \
    else { WAITV(0); }                                                         \
    LGKM0;                                                                     \
    __builtin_amdgcn_s_barrier(); FENCE;                                       \
    if (t_ + 4 < H1_NT) {                                                      \
      SLD[0] = *(const float4*)(Ap + (t_ + 4) * 32);                           \
      SLD[1] = *(const float4*)(Ap + (t_ + 4) * 32 + 4);                       \
    }                                                                          \
    if (t_ + 2 < H1_NT) {                                                      \
      gl_lds16(Bp0 + (t_ + 2) * 32, &Bs[(t_ + 2) & 3][wid * 1024]);            \
      gl_lds16(Bp1 + (t_ + 2) * 32, &Bs[(t_ + 2) & 3][wid * 1024 + 512]);      \
    }                                                                          \
    if (t_ + 1 < H1_NT) { cvtwrite(SCV, t_ + 1); }                             \
    __builtin_amdgcn_s_setprio(1);                                             \
    compute(t_ & 1, t_ & 3);                                                   \
    __builtin_amdgcn_s_setprio(0);                                             \
  }

  for (int tb = 0; tb < H1_NT; tb += 4) {
    H1_ITER(tb + 0, S0, S1);
    H1_ITER(tb + 1, S1, S2);
    H1_ITER(tb + 2, S2, S3);
    H1_ITER(tb + 3, S3, S0);
  }
#undef H1_ITER

  float* o = part + (size_t)ksl * NROW * NH1;
  #pragma unroll
  for (int m = 0; m < 4; m++) {
    const int row = bm0 + wr * 64 + m * 16 + hi * 4;
    #pragma unroll
    for (int n = 0; n < 4; n++) {
      const int col = wc * 64 + n * 16 + rr;
      #pragma unroll
      for (int r = 0; r < 4; r++)
        o[(size_t)(row + r) * NH1 + col] = acc[m][n][r];
    }
  }
}

// ---------------------------------------------------------------------------
// gemm_h2: part[4][16384][128] = adjBF @ s2. 8 waves, 128x128 block, BK=32.
// Both operands via global_load_lds, 4 bufs, depth-3, steady vmcnt(4).
// 64 KB LDS + <=128 VGPR -> 2 blocks/CU, 4 waves/SIMD.
#define H2_NT 128

__global__ __launch_bounds__(512, 4) void gemm_h2(
    const ushort* __restrict__ adjBF, const ushort* __restrict__ s2T,
    float* __restrict__ part)
{
  __shared__ ushort As[4][4096];   // 4 bufs x 8 tiles x 512
  __shared__ ushort Bs[4][4096];

  const int t = threadIdx.x, l = t & 63, wid = t >> 6;
  const int rr = l & 15, hi = l >> 4;
  const int wr = wid >> 1, wc = wid & 1;       // wave grid 4M x 2N

  const int cpx = gridDim.x >> 3;
  const int flat = (blockIdx.x & 7) * cpx + (blockIdx.x >> 3);
  const int m_blk = flat & 127;
  const int ksl = flat >> 7;                   // 0..3
  const int bm0 = m_blk * 128;
  const int kbase = ksl * 4096;

  const ushort* Apg = adjBF + (size_t)(bm0 + wid * 16 + rr) * NROW + kbase + hi * 8;
  const ushort* Bpg = s2T + (size_t)(wid * 16 + rr) * NROW + kbase + hi * 8;

  f32x4 acc[2][4] = {};

  auto stage = [&](int k) {
    gl_lds16(Apg + k * 32, &As[k & 3][wid * 512]);
    gl_lds16(Bpg + k * 32, &Bs[k & 3][wid * 512]);
  };
  auto compute = [&](int bb) {
    short8 af[2], bf4[4];
    #pragma unroll
    for (int m = 0; m < 2; m++)
      af[m] = *(const short8*)&As[bb][(wr * 2 + m) * 512 + l * 8];
    #pragma unroll
    for (int n = 0; n < 4; n++)
      bf4[n] = *(const short8*)&Bs[bb][(wc * 4 + n) * 512 + l * 8];
    #pragma unroll
    for (int m = 0; m < 2; m++)
      #pragma unroll
      for (int n = 0; n < 4; n++)
        acc[m][n] = __builtin_amdgcn_mfma_f32_16x16x32_bf16(af[m], bf4[n], acc[m][n], 0, 0, 0);
  };

  stage(0); stage(1); stage(2);
  for (int t_ = 0; t_ < H2_NT; t_++) {
    if (t_ < H2_NT - 2) { WAITV(4); } else { WAITV(0); }
    __builtin_amdgcn_s_barrier(); FENCE;
    if (t_ + 3 < H2_NT) stage(t_ + 3);
    __builtin_amdgcn_s_setprio(1);
    compute(t_ & 3);
    __builtin_amdgcn_s_setprio(0);
  }

  float* o = part + (size_t)ksl * NROW * NH2;
  #pragma unroll
  for (int m = 0; m < 2; m++) {
    const int row = bm0 + wr * 32 + m * 16 + hi * 4;
    #pragma unroll
    for (int n = 0; n < 4; n++) {
      const int col = wc * 64 + n * 16 + rr;
      #pragma unroll
      for (int r = 0; r < 4; r++)
        o[(size_t)(row + r) * NH2 + col] = acc[m][n][r];
    }
  }
}

// ---------------------------------------------------------------------------
// gemm_fin: part[8][16384][16] = adjBF @ s3 (s3T padded to 16 cols).
// Pure register streaming: no LDS, no barriers; B is L3-resident.
__global__ __launch_bounds__(256, 4) void gemm_fin(
    const ushort* __restrict__ adjBF, const ushort* __restrict__ s3T,
    float* __restrict__ part)
{
  const int t = threadIdx.x, l = t & 63, wid = t >> 6;   // 4 waves
  const int rr = l & 15, hi = l >> 4;

  const int cpx = gridDim.x >> 3;
  const int flat = (blockIdx.x & 7) * cpx + (blockIdx.x >> 3);
  const int m_blk = flat & 127;
  const int ksl = flat >> 7;                   // 0..7
  const int bm0 = m_blk * 128;
  const int kbase = ksl * 2048;

  const ushort* A0 = adjBF + (size_t)(bm0 + wid * 32 + rr) * NROW + kbase + hi * 8;
  const ushort* A1 = A0 + (size_t)16 * NROW;
  const ushort* Bp = s3T + (size_t)rr * NROW + kbase + hi * 8;

  f32x4 acc0 = {}, acc1 = {};
  #pragma unroll 8
  for (int k = 0; k < 64; k++) {
    short8 a0 = *(const short8*)(A0 + k * 32);
    short8 a1 = *(const short8*)(A1 + k * 32);
    short8 b  = *(const short8*)(Bp + k * 32);
    acc0 = __builtin_amdgcn_mfma_f32_16x16x32_bf16(a0, b, acc0, 0, 0, 0);
    acc1 = __builtin_amdgcn_mfma_f32_16x16x32_bf16(a1, b, acc1, 0, 0, 0);
  }

  float* o = part + (size_t)ksl * NROW * 16;
  #pragma unroll
  for (int r = 0; r < 4; r++) {
    o[(size_t)(bm0 + wid * 32 + hi * 4 + r) * 16 + rr] = acc0[r];
    o[(size_t)(bm0 + wid * 32 + 16 + hi * 4 + r) * 16 + rr] = acc1[r];
  }
}

// out[M][N] bf16 = relu(sum_k part[k][M][N] + bias[col]); vectorized by 4
__global__ __launch_bounds__(256) void reduce_relu(
    const float* __restrict__ part, const float* __restrict__ bias,
    ushort* __restrict__ out, const int MN, const int N, const int KS) {
  const int i4 = (blockIdx.x * 256 + threadIdx.x) * 4;
  if (i4 >= MN) return;
  float4 s = *(const float4*)(part + i4);
  for (int k = 1; k < KS; k++) {
    float4 p = *(const float4*)(part + (size_t)k * MN + i4);
    s.x += p.x; s.y += p.y; s.z += p.z; s.w += p.w;
  }
  const int col = i4 % N;
  float4 b = *(const float4*)(bias + col);
  ushort4 v;
  v.x = f2bf(fmaxf(s.x + b.x, 0.0f));
  v.y = f2bf(fmaxf(s.y + b.y, 0.0f));
  v.z = f2bf(fmaxf(s.z + b.z, 0.0f));
  v.w = f2bf(fmaxf(s.w + b.w, 0.0f));
  *(ushort4*)(out + i4) = v;
}

// s3T[16][NROW] bf16 = (h2 @ W3)^T, rows 8..15 zero-padded. 64-thr blocks.
__global__ __launch_bounds__(64) void mm_small(
    const ushort* __restrict__ h2, const float* __restrict__ W3,
    ushort* __restrict__ s3T) {
  __shared__ float w[NH2 * NCLS];
  for (int i = threadIdx.x; i < NH2 * NCLS; i += 64) w[i] = W3[i];
  __syncthreads();
  const int m = blockIdx.x * 64 + threadIdx.x;
  float acc[8] = {};
  const ushort* row = h2 + (size_t)m * NH2;
  #pragma unroll
  for (int c = 0; c < NH2 / 8; c++) {
    short8 v = *(const short8*)(row + c * 8);
    #pragma unroll
    for (int j = 0; j < 8; j++) {
      float h = bf2f((ushort)v[j]);
      const int k = c * 8 + j;
      #pragma unroll
      for (int n = 0; n < 8; n++) acc[n] += h * w[k * 8 + n];
    }
  }
  #pragma unroll
  for (int n = 0; n < 8; n++) s3T[(size_t)n * NROW + m] = f2bf(acc[n]);
  #pragma unroll
  for (int n = 8; n < 16; n++) s3T[(size_t)n * NROW + m] = 0;
}

// out[NROW][8] = log_softmax(sum_ksl part + b3), KS=8
__global__ __launch_bounds__(256) void final_reduce(
    const float* __restrict__ part, const float* __restrict__ b3,
    float* __restrict__ out) {
  const int m = blockIdx.x * 256 + threadIdx.x;
  float4 s0 = make_float4(0, 0, 0, 0), s1 = make_float4(0, 0, 0, 0);
  #pragma unroll
  for (int k = 0; k < 8; k++) {
    const float4* p = (const float4*)(part + ((size_t)k * NROW + m) * 16);
    float4 a = p[0], b = p[1];
    s0.x += a.x; s0.y += a.y; s0.z += a.z; s0.w += a.w;
    s1.x += b.x; s1.y += b.y; s1.z += b.z; s1.w += b.w;
  }
  float v[8];
  v[0] = s0.x + b3[0]; v[1] = s0.y + b3[1]; v[2] = s0.z + b3[2]; v[3] = s0.w + b3[3];
  v[4] = s1.x + b3[4]; v[5] = s1.y + b3[5]; v[6] = s1.z + b3[6]; v[7] = s1.w + b3[7];
  float mx = v[0];
  #pragma unroll
  for (int n = 1; n < 8; n++) mx = fmaxf(mx, v[n]);
  float s = 0.0f;
  #pragma unroll
  for (int n = 0; n < 8; n++) s += expf(v[n] - mx);
  const float lse = logf(s) + mx;
  float4* o = (float4*)(out + (size_t)m * 8);
  o[0] = make_float4(v[0] - lse, v[1] - lse, v[2] - lse, v[3] - lse);
  o[1] = make_float4(v[4] - lse, v[5] - lse, v[6] - lse, v[7] - lse);
}

extern "C" void kernel_launch(void* const* d_in, const int* in_sizes, int n_in,
                              void* d_out, int out_size, void* d_ws, size_t ws_size,
                              hipStream_t stream) {
  const float* x   = (const float*)d_in[0];
  const float* adj = (const float*)d_in[1];
  const float* W1  = (const float*)d_in[2];
  const float* b1  = (const float*)d_in[3];
  const float* W2  = (const float*)d_in[4];
  const float* b2  = (const float*)d_in[5];
  const float* W3  = (const float*)d_in[6];
  const float* b3  = (const float*)d_in[7];
  float* out = (float*)d_out;

  char* ws = (char*)d_ws;
  size_t off = 0;
  ushort* W1T = (ushort*)(ws + off); off += (size_t)NH1 * NFEATC * 2;    // 256 KB
  ushort* W2T = (ushort*)(ws + off); off += (size_t)NH2 * NH1 * 2;      // 64 KB
  ushort* s1T = (ushort*)(ws + off); off += (size_t)NH1 * NROW * 2;     // 8 MiB
  ushort* h1  = (ushort*)(ws + off); off += (size_t)NROW * NH1 * 2;     // 8 MiB
  ushort* s2T = (ushort*)(ws + off); off += (size_t)NH2 * NROW * 2;     // 4 MiB
  ushort* h2  = (ushort*)(ws + off); off += (size_t)NROW * NH2 * 2;     // 4 MiB
  ushort* s3T = (ushort*)(ws + off); off += (size_t)16 * NROW * 2;      // 512 KB
  float*  part = (float*)(ws + off); off += (size_t)4 * NROW * NH1 * 4; // 64 MiB
  ushort* adjBF = (ushort*)(ws + off); off += (size_t)NROW * NROW * 2;  // 512 MiB

  transpose_conv<<<(NFEATC * NH1 + 255) / 256, 256, 0, stream>>>(W1, W1T, NFEATC, NH1);
  transpose_conv<<<(NH1 * NH2 + 255) / 256, 256, 0, stream>>>(W2, W2T, NH1, NH2);

  // s1T[256][16384] = (x @ W1)^T : 512 blocks
  gemm_pipe<64, 128, 32, 64, 1, true, 1, 2><<<512, 256, 0, stream>>>(
      x, W1T, s1T, nullptr, 256, 2, NROW, NH1, NFEATC);
  // part[4][16384][256] = adj @ s1 (counted-vmcnt pipeline) + adjBF writeout
  gemm_h1<<<512, 512, 0, stream>>>(adj, s1T, part, adjBF);
  // h1 = relu(sum part + b1)
  reduce_relu<<<NROW * NH1 / 4 / 256, 256, 0, stream>>>(
      part, b1, h1, NROW * NH1, NH1, 4);
  // s2T[128][16384] = (h1 @ W2)^T : 256 blocks
  gemm_pipe<64, 128, 32, 64, 1, false, 1, 2><<<256, 256, 0, stream>>>(
      h1, W2T, s2T, nullptr, 256, 1, NROW, NH2, NH1);
  // part[4][16384][128] = adjBF @ s2 (counted-vmcnt pipeline)
  gemm_h2<<<512, 512, 0, stream>>>(adjBF, s2T, part);
  // h2 = relu(sum part + b2)
  reduce_relu<<<NROW * NH2 / 4 / 256, 256, 0, stream>>>(
      part, b2, h2, NROW * NH2, NH2, 4);
  // s3T[16][16384] = (h2 @ W3)^T (bf16, zero-padded to 16 rows)
  mm_small<<<NROW / 64, 64, 0, stream>>>(h2, W3, s3T);
  // part[8][16384][16] = adjBF @ s3 (no-barrier streaming)
  gemm_fin<<<1024, 256, 0, stream>>>(adjBF, s3T, part);
  // out = log_softmax(sum part + b3)
  final_reduce<<<NROW / 256, 256, 0, stream>>>(part, b3, out);
}